// Round 8
// baseline (132.100 us; speedup 1.0000x reference)
//
#include <hip/hip_runtime.h>
#include <stdint.h>

// Problem constants (fixed by reference)
#define NTOK 8192
#define DM   1024
#define NE   8
#define NR   16
#define KX   1152   // DM + NE*NR = 1024 + 128

typedef short bf16x8 __attribute__((ext_vector_type(8)));
typedef float f32x4  __attribute__((ext_vector_type(4)));
typedef float f32x16 __attribute__((ext_vector_type(16)));

__device__ __forceinline__ unsigned short f2bf(float f) {
    union { float f; unsigned u; } v; v.f = f;
    unsigned r = v.u + 0x7fffu + ((v.u >> 16) & 1u);   // RNE
    return (unsigned short)(r >> 16);
}

__device__ __forceinline__ void gld16(const void* g, void* l) {
    __builtin_amdgcn_global_load_lds((__attribute__((address_space(1))) void*)g,
                                     (__attribute__((address_space(3))) void*)l,
                                     16, 0, 0);
}

// ---------------------------------------------------------------------------
// prep: fused role-by-block kernel (R5-proven).
//  blocks [0,2048):     fp32 gating (wave/token) + x -> bf16 into Xext[:,0:1024]
//  blocks [2048,3072):  WBext[j][0:1152] = [W_base[j][:] | B[:, j]]  (bf16)
//  blocks [3072,3200):  At[p][0:1024] = A[e][:][r] transpose        (bf16)
// ---------------------------------------------------------------------------
__global__ __launch_bounds__(256) void prep(const float* __restrict__ x,
                                            const float* __restrict__ Wg,
                                            const float* __restrict__ Asrc,
                                            const float* __restrict__ Bsrc,
                                            const float* __restrict__ Wb,
                                            float* __restrict__ combine,
                                            unsigned short* __restrict__ Xext,
                                            unsigned short* __restrict__ WBext,
                                            unsigned short* __restrict__ At) {
    const int b = blockIdx.x;
    const int t = threadIdx.x;

    if (b < 2048) {
        const int lane = t & 63;
        const int w = t >> 6;
        const int n = b * 4 + w;

        const float4* x4 = (const float4*)(x + (size_t)n * DM);
        float4 xv[4];
        #pragma unroll
        for (int i = 0; i < 4; ++i) xv[i] = x4[i * 64 + lane];

        float acc[NE];
        #pragma unroll
        for (int e = 0; e < NE; ++e) {
            const float4* wg4 = (const float4*)(Wg + (size_t)e * DM);
            float s = 0.f;
            #pragma unroll
            for (int i = 0; i < 4; ++i) {
                float4 g = wg4[i * 64 + lane];
                s += xv[i].x * g.x + xv[i].y * g.y + xv[i].z * g.z + xv[i].w * g.w;
            }
            acc[e] = s;
        }
        #pragma unroll
        for (int off = 32; off >= 1; off >>= 1) {
            #pragma unroll
            for (int e = 0; e < NE; ++e) acc[e] += __shfl_xor(acc[e], off, 64);
        }
        // top-2, lowest index wins ties (matches lax.top_k)
        float best = acc[0]; int bi = 0;
        #pragma unroll
        for (int e = 1; e < NE; ++e) if (acc[e] > best) { best = acc[e]; bi = e; }
        float sec = -1e30f; int si = 0;
        #pragma unroll
        for (int e = 0; e < NE; ++e) if (e != bi && acc[e] > sec) { sec = acc[e]; si = e; }
        const float ed = __expf(sec - best);
        const float w0 = 1.f / (1.f + ed);
        const float w1 = ed * w0;
        if (lane < NE)
            combine[n * NE + lane] = (lane == bi) ? w0 : ((lane == si) ? w1 : 0.f);

        unsigned short* xrow = Xext + (size_t)n * KX;
        #pragma unroll
        for (int i = 0; i < 4; ++i) {
            ushort4 o;
            o.x = f2bf(xv[i].x); o.y = f2bf(xv[i].y);
            o.z = f2bf(xv[i].z); o.w = f2bf(xv[i].w);
            *(ushort4*)(xrow + (i * 64 + lane) * 4) = o;
        }
    } else if (b < 3072) {
        const int j = b - 2048;
        unsigned short* row = WBext + (size_t)j * KX;
        float4 v = ((const float4*)(Wb + (size_t)j * DM))[t];
        ushort4 o;
        o.x = f2bf(v.x); o.y = f2bf(v.y); o.z = f2bf(v.z); o.w = f2bf(v.w);
        *(ushort4*)(row + t * 4) = o;
        if (t < 128) row[DM + t] = f2bf(Bsrc[(size_t)t * DM + j]);   // B[e][r][j]
    } else {
        const int p = b - 3072;
        const int e = p >> 4, r = p & 15;
        for (int d = t; d < DM; d += 256)
            At[(size_t)p * DM + d] = f2bf(Asrc[e * (DM * NR) + d * NR + r]);
    }
}

// ---------------------------------------------------------------------------
// hall: Hfull = (x_bf16 @ At^T) * combine -> bf16 into Xext[:, 1024:1152]
//   512 blocks (32 tok x 64 col, 2 blocks/CU), single-barrier dbuf K-loop.
//   (unchanged from R7)
// ---------------------------------------------------------------------------
__global__ __launch_bounds__(256) void hall_kernel(unsigned short* Xext,
                                                   const unsigned short* __restrict__ At,
                                                   const float* __restrict__ combine) {
    __shared__ __align__(16) unsigned short lds[12288];
    const int t = threadIdx.x;
    const int lane = t & 63;
    const int w = t >> 6;
    const int quad = lane >> 4;
    const int l15 = lane & 15;
    const int bid = blockIdx.x;        // 512
    const int bm = bid >> 1;
    const int cb = bid & 1;
    const int n0 = bm * 32;
    const int wm = (w & 1) * 16;
    const int wn = (w >> 1) * 32;

    const int srow = t >> 3;
    const int seg  = (t & 7) ^ (srow & 7);

    const unsigned short* gX  = Xext + (size_t)(n0 + srow) * KX + seg * 8;
    const unsigned short* gA0 = At + (size_t)(cb * 64 + srow) * DM + seg * 8;
    const unsigned short* gA1 = At + (size_t)(cb * 64 + 32 + srow) * DM + seg * 8;

    f32x4 acc[2] = {};

    #define HALL_STAGE(k0, s)                                              \
        gld16(gX  + (k0), (char*)lds + (s) * 12288 + w * 1024);            \
        gld16(gA0 + (k0), (char*)lds + (s) * 12288 + 4096 + w * 1024);     \
        gld16(gA1 + (k0), (char*)lds + (s) * 12288 + 8192 + w * 1024);

    #define HALL_COMPUTE(s)                                                        \
        {                                                                          \
            const int xo = (s) * 6144, ao = (s) * 6144 + 2048;                     \
            _Pragma("unroll")                                                      \
            for (int kk = 0; kk < 2; ++kk) {                                       \
                const int gs = kk * 4 + quad;                                      \
                const int sw = (gs ^ (l15 & 7)) * 8;                               \
                bf16x8 a = *(const bf16x8*)&lds[xo + (wm + l15) * 64 + sw];        \
                _Pragma("unroll")                                                  \
                for (int jf = 0; jf < 2; ++jf) {                                   \
                    bf16x8 bb = *(const bf16x8*)&lds[ao + (wn + jf * 16 + l15) * 64 + sw]; \
                    acc[jf] = __builtin_amdgcn_mfma_f32_16x16x32_bf16(a, bb, acc[jf], 0, 0, 0); \
                }                                                                  \
            }                                                                      \
        }

    HALL_STAGE(0, 0);
    for (int k0 = 0; k0 < DM; k0 += 128) {
        __syncthreads();
        HALL_STAGE(k0 + 64, 1);
        HALL_COMPUTE(0);
        __syncthreads();
        if (k0 + 128 < DM) { HALL_STAGE(k0 + 128, 0); }
        HALL_COMPUTE(1);
    }

    #pragma unroll
    for (int jf = 0; jf < 2; ++jf) {
        const int p = cb * 64 + wn + jf * 16 + l15;
        const int e = p >> 4;
        #pragma unroll
        for (int v = 0; v < 4; ++v) {
            const int n = n0 + wm + quad * 4 + v;
            const float val = acc[jf][v] * combine[n * NE + e];
            Xext[(size_t)n * KX + DM + p] = f2bf(val);
        }
    }
    #undef HALL_STAGE
    #undef HALL_COMPUTE
}

// ---------------------------------------------------------------------------
// mgemm: out[8192][1024] = Xext[8192][1152] @ WBext[1024][1152]^T + bias
//   128x128 tile, BK=64 dbuf single-barrier K-loop (R7), but inner product
//   switched to v_mfma_f32_32x32x16_bf16: +20% matrix-pipe FLOP/cyc (m119:
//   2495 vs 2075 TF) and half the MFMA issues / frag loads per FLOP.
//   Wave = 64x64 via 2x2 blocks of 32x32, 4 x f32x16 acc (64 VGPR).
//   A/B frag: lane reads row (lane&31), K-seg kk*2+(lane>>5) — one 16 B
//   XOR-swizzled LDS seg, conflict-free as before.
//   C/D layout (m74/m101): col=lane&31, row=(reg&3)+8*(reg>>2)+4*(lane>>5).
// ---------------------------------------------------------------------------
__global__ __launch_bounds__(256, 2) void mgemm(const unsigned short* __restrict__ Xext,
                                                const unsigned short* __restrict__ WBext,
                                                const float* __restrict__ bias,
                                                float* __restrict__ out) {
    __shared__ __align__(16) unsigned short lds[32768];   // 64 KB
    const int t = threadIdx.x;
    const int lane = t & 63;
    const int w = t >> 6;
    const int l31 = lane & 31;
    const int kh  = lane >> 5;          // k-half selector for 32x32 frags

    const int bid = blockIdx.x;          // 512
    const int xcd = bid & 7;
    const int loc = bid >> 3;
    const int bm = xcd * 8 + (loc & 7);  // 0..63
    const int bn = loc >> 3;             // 0..7

    const int wm = (w & 1) * 64;
    const int wn = (w >> 1) * 64;

    f32x16 acc[2][2] = {};               // [ib][jb] 32x32 blocks

    const int srow = t >> 3;                     // 0..31
    const int seg  = (t & 7) ^ (srow & 7);       // XOR swizzle (global side)
    const unsigned short* gA = Xext  + (size_t)(bm * 128 + srow) * KX + seg * 8;
    const unsigned short* gB = WBext + (size_t)(bn * 128 + srow) * KX + seg * 8;

    #define MG_STAGE(k0, s)                                                          \
        _Pragma("unroll")                                                            \
        for (int c = 0; c < 4; ++c) {                                                \
            gld16(gA + (size_t)c * 32 * KX + (k0), (char*)lds + (s) * 32768 + c * 4096 + w * 1024);        \
            gld16(gB + (size_t)c * 32 * KX + (k0), (char*)lds + (s) * 32768 + 16384 + c * 4096 + w * 1024);\
        }

    // Per 64-K chunk: kk = 0..3 (K=16 each). Lane's frag: row=base+l31,
    // global seg gs = kk*2 + kh, LDS pos = gs ^ (row&7) = gs ^ (l31&7).
    #define MG_COMPUTE(s)                                                            \
        {                                                                            \
            const int ao = (s) * 16384, bo = (s) * 16384 + 8192;                     \
            _Pragma("unroll")                                                        \
            for (int kk = 0; kk < 4; ++kk) {                                         \
                const int gs = kk * 2 + kh;                                          \
                const int sw = (gs ^ (l31 & 7)) * 8;                                 \
                bf16x8 a[2], b[2];                                                   \
                _Pragma("unroll")                                                    \
                for (int i = 0; i < 2; ++i)                                          \
                    a[i] = *(const bf16x8*)&lds[ao + (wm + i * 32 + l31) * 64 + sw]; \
                _Pragma("unroll")                                                    \
                for (int j = 0; j < 2; ++j)                                          \
                    b[j] = *(const bf16x8*)&lds[bo + (wn + j * 32 + l31) * 64 + sw]; \
                _Pragma("unroll")                                                    \
                for (int i = 0; i < 2; ++i)                                          \
                    _Pragma("unroll")                                                \
                    for (int j = 0; j < 2; ++j)                                      \
                        acc[i][j] = __builtin_amdgcn_mfma_f32_32x32x16_bf16(a[i], b[j], acc[i][j], 0, 0, 0); \
            }                                                                        \
        }

    MG_STAGE(0, 0);
    for (int k0 = 0; k0 < KX; k0 += 128) {       // 9 macro-iters (18 chunks)
        __syncthreads();
        MG_STAGE(k0 + 64, 1);
        MG_COMPUTE(0);
        __syncthreads();
        if (k0 + 128 < KX) { MG_STAGE(k0 + 128, 0); }
        MG_COMPUTE(1);
    }
    #undef MG_STAGE
    #undef MG_COMPUTE

    // Epilogue: per-wave 64x64 LDS transpose -> coalesced float4 stores.
    // 32x32 C/D: row = ib*32 + (reg&3) + 8*(reg>>2) + 4*kh, col = jb*32 + l31.
    __syncthreads();
    float* lf = (float*)lds + w * 4096;
    #pragma unroll
    for (int jb = 0; jb < 2; ++jb) {
        const float bv = bias[bn * 128 + wn + jb * 32 + l31];
        #pragma unroll
        for (int ib = 0; ib < 2; ++ib)
            #pragma unroll
            for (int reg = 0; reg < 16; ++reg) {
                const int row_l = ib * 32 + (reg & 3) + 8 * (reg >> 2) + 4 * kh;
                const int col_l = jb * 32 + l31;
                const int col_s = col_l ^ ((row_l & 1) << 4);   // 2-way banks
                lf[row_l * 64 + col_s] = acc[ib][jb][reg] + bv;
            }
    }
    __builtin_amdgcn_s_waitcnt(0);
    #pragma unroll
    for (int rr = 0; rr < 16; ++rr) {
        const int row_r = rr * 4 + (lane >> 4);
        const int col4  = (lane & 15) * 4;
        const int col4s = col4 ^ ((row_r & 1) << 4);
        float4 vv = *(const float4*)&lf[row_r * 64 + col4s];
        *(float4*)&out[(size_t)(bm * 128 + wm + row_r) * DM + bn * 128 + wn + col4] = vv;
    }
}

// ---------------------------------------------------------------------------
extern "C" void kernel_launch(void* const* d_in, const int* in_sizes, int n_in,
                              void* d_out, int out_size, void* d_ws, size_t ws_size,
                              hipStream_t stream) {
    const float* x  = (const float*)d_in[0];   // [8192,1024]
    const float* Wg = (const float*)d_in[1];   // [8,1024]
    const float* A  = (const float*)d_in[2];   // [8,1024,16]
    const float* B  = (const float*)d_in[3];   // [8,16,1024]
    const float* Wb = (const float*)d_in[4];   // [1024,1024]
    const float* bb = (const float*)d_in[5];   // [1024]
    float* out = (float*)d_out;

    char* ws = (char*)d_ws;
    float*          combine = (float*)ws;                                   // 262144 B
    unsigned short* Xext    = (unsigned short*)(ws + 262144);               // 18874368 B
    unsigned short* WBext   = (unsigned short*)(ws + 262144 + 18874368);    // 2359296 B
    unsigned short* At      = (unsigned short*)(ws + 262144 + 18874368 + 2359296); // 262144 B

    hipLaunchKernelGGL(prep,        dim3(3200), dim3(256), 0, stream,
                       x, Wg, A, B, Wb, combine, Xext, WBext, At);
    hipLaunchKernelGGL(hall_kernel, dim3(512),  dim3(256), 0, stream, Xext, At, combine);
    hipLaunchKernelGGL(mgemm,       dim3(512),  dim3(256), 0, stream, Xext, WBext, bb, out);
}